// Round 16
// baseline (5785.727 us; speedup 1.0000x reference)
//
#include <hip/hip_runtime.h>
#include <cstdint>
#include <cstddef>

#pragma clang fp contract(off)

// ===================== round-to-round toggles =====================
#define PRNG_PARTITIONABLE 1   // confirmed correct in R1 (absmax 0.0)
// sigmoid exp-form; tanh = XLA poly clamp +-9; gemms = sequential-k fmaf;
// score reduce = strict sequential per (b,s) lane; mask compaction (R7);
// cross-batch P4 packing (R13); gated aB-shadow (R15); fdiv_rn
// (R6/R8/R11 bit-exact). R1-R15 pass.
// R16: (a) shadow gate widened to nfree>=2 (SHADOW_FROM 64->33; capacity:
// 4 chains/lane ~2.6k issue < P4a ~4.4k; R14's overflow was nfree=1);
// (b) update phase merged into P4b (wave g copies its own batch's enc row
// — loc is wave-uniform there) deleting 1 of 6 barriers/step.
// ==================================================================

#define INFTY_F 1.0e8f
#define TINY_F 1.17549435e-38f

#define SHADOW_FROM 33   // steps >= this consume aB_s (shadow ran at step-1)

// In-range correctly-rounded f32 divide: LLVM's FDIV32 lowering minus
// div_scale/div_fixup (pass-through for normal mid-range operands; here
// q in [4.9e-3, 53], |num| <= 500). On-device bit-exact R6/R8/R11.
__device__ __forceinline__ float fdiv_rn(float n, float q) {
  float y0 = __builtin_amdgcn_rcpf(q);
  float y  = fmaf(fmaf(-q, y0, 1.0f), y0, y0);
  float r0 = n * y;
  float e0 = fmaf(-q, r0, n);
  float r1 = fmaf(e0, y, r0);
  float e1 = fmaf(-q, r1, n);
  return fmaf(e1, y, r1);
}

// ---------------- threefry2x32 (jax exact) ----------------
__device__ __forceinline__ void tf2x32(uint32_t k0, uint32_t k1, uint32_t x0, uint32_t x1,
                                       uint32_t& o0, uint32_t& o1) {
  uint32_t ks2 = k0 ^ k1 ^ 0x1BD11BDAu;
  uint32_t v0 = x0 + k0, v1 = x1 + k1;
#define TF_R(r) { v0 += v1; v1 = (v1 << (r)) | (v1 >> (32 - (r))); v1 ^= v0; }
  TF_R(13) TF_R(15) TF_R(26) TF_R(6)
  v0 += k1;  v1 += ks2 + 1u;
  TF_R(17) TF_R(29) TF_R(16) TF_R(24)
  v0 += ks2; v1 += k0 + 2u;
  TF_R(13) TF_R(15) TF_R(26) TF_R(6)
  v0 += k0;  v1 += k1 + 3u;
  TF_R(17) TF_R(29) TF_R(16) TF_R(24)
  v0 += k1;  v1 += ks2 + 4u;
  TF_R(13) TF_R(15) TF_R(26) TF_R(6)
  v0 += ks2; v1 += k0 + 5u;
#undef TF_R
  o0 = v0; o1 = v1;
}

__device__ __forceinline__ uint32_t random_bits32(uint32_t k0, uint32_t k1, uint32_t j) {
#if PRNG_PARTITIONABLE
  uint32_t o0, o1;
  tf2x32(k0, k1, 0u, j, o0, o1);
  return o0 ^ o1;
#else
  uint32_t o0, o1;
  if (j < 131072u) { tf2x32(k0, k1, j, j + 131072u, o0, o1); return o0; }
  else             { tf2x32(k0, k1, j - 131072u, j, o0, o1); return o1; }
#endif
}

// ---------------- XLA math replicas ----------------
__device__ __forceinline__ float xla_tanhf(float x) {
  float xc = fminf(fmaxf(x, -9.0f), 9.0f);
  float x2 = xc * xc;
  float p = -2.76076847742355e-16f;
  p = (p * x2) + 2.00018790482477e-13f;
  p = (p * x2) + -8.60467152213735e-11f;
  p = (p * x2) + 5.12229709037114e-08f;
  p = (p * x2) + 1.48572235717979e-05f;
  p = (p * x2) + 6.37261928875436e-04f;
  p = (p * x2) + 4.89352455891786e-03f;
  float num = xc * p;
  float q = 1.19825839466702e-06f;
  q = (q * x2) + 1.18534705686654e-04f;
  q = (q * x2) + 2.26843463243900e-03f;
  q = (q * x2) + 4.89352518554385e-03f;
  float r = fdiv_rn(num, q);           // q in [4.9e-3, 53]: verified range
  return (fabsf(x) < 0.0004f) ? x : r;
}

// scalar-pair tanh used in P4; per-element ops IEEE-identical to xla_tanhf.
__device__ __forceinline__ void xla_tanh2(float xa, float xb, float& ra, float& rb) {
  float xca = fminf(fmaxf(xa, -9.0f), 9.0f);
  float xcb = fminf(fmaxf(xb, -9.0f), 9.0f);
  float x2a = xca * xca, x2b = xcb * xcb;
  float pa = -2.76076847742355e-16f, pb = -2.76076847742355e-16f;
  pa = (pa * x2a) + 2.00018790482477e-13f;  pb = (pb * x2b) + 2.00018790482477e-13f;
  pa = (pa * x2a) + -8.60467152213735e-11f; pb = (pb * x2b) + -8.60467152213735e-11f;
  pa = (pa * x2a) + 5.12229709037114e-08f;  pb = (pb * x2b) + 5.12229709037114e-08f;
  pa = (pa * x2a) + 1.48572235717979e-05f;  pb = (pb * x2b) + 1.48572235717979e-05f;
  pa = (pa * x2a) + 6.37261928875436e-04f;  pb = (pb * x2b) + 6.37261928875436e-04f;
  pa = (pa * x2a) + 4.89352455891786e-03f;  pb = (pb * x2b) + 4.89352455891786e-03f;
  float na = xca * pa, nb = xcb * pb;
  float qa = 1.19825839466702e-06f, qb = 1.19825839466702e-06f;
  qa = (qa * x2a) + 1.18534705686654e-04f; qb = (qb * x2b) + 1.18534705686654e-04f;
  qa = (qa * x2a) + 2.26843463243900e-03f; qb = (qb * x2b) + 2.26843463243900e-03f;
  qa = (qa * x2a) + 4.89352518554385e-03f; qb = (qb * x2b) + 4.89352518554385e-03f;
  float da = fdiv_rn(na, qa), db = fdiv_rn(nb, qb);
  ra = (fabsf(xa) < 0.0004f) ? xa : da;
  rb = (fabsf(xb) < 0.0004f) ? xb : db;
}

__device__ __forceinline__ float xla_expf(float x) {
  x = fminf(x, 88.3762626647950f);
  x = fmaxf(x, -88.3762626647949f);
  float m = floorf((x * 1.44269504088896341f) + 0.5f);
  float r = x - (m * 0.693359375f);
  r = r - (m * -2.12194440e-4f);
  float r2 = r * r;
  float y = 1.9875691500E-4f;
  y = (y * r) + 1.3981999507E-3f;
  y = (y * r) + 8.3334519073E-3f;
  y = (y * r) + 4.1665795894E-2f;
  y = (y * r) + 1.6666665459E-1f;
  y = (y * r) + 5.0000001201E-1f;
  y = (y * r2) + r;
  y = y + 1.0f;
  int mi = (int)m;
  float s = __uint_as_float((uint32_t)((mi + 127) << 23));
  return y * s;
}

__device__ __forceinline__ float xla_sigmoidf(float x) {
  return 1.0f / (1.0f + xla_expf(-x));   // keep compiler div (denom can be huge)
}

__device__ __forceinline__ float xla_logf(float x) {
  uint32_t b = __float_as_uint(x);
  float e = (float)((int)(b >> 23) - 126);
  float m = __uint_as_float((b & 0x007fffffu) | 0x3f000000u);
  bool mlt = (m < 0.707106781186547524f);
  float tmp = mlt ? m : 0.0f;
  e = e - (mlt ? 1.0f : 0.0f);
  float xx = (m - 1.0f) + tmp;
  float z = xx * xx;
  float y = 7.0376836292E-2f;
  y = (y * xx) + -1.1514610310E-1f;
  y = (y * xx) + 1.1676998740E-1f;
  y = (y * xx) + -1.2420140846E-1f;
  y = (y * xx) + 1.4249322787E-1f;
  y = (y * xx) + -1.6668057665E-1f;
  y = (y * xx) + 2.0000714765E-1f;
  y = (y * xx) + -2.4999993993E-1f;
  y = (y * xx) + 3.3333331174E-1f;
  y = y * xx;
  y = y * z;
  y = y + (e * -2.12194440e-4f);
  y = y - (z * 0.5f);
  float res = xx + y;
  res = res + (e * 0.693359375f);
  return res;
}

__device__ __forceinline__ float gumbel_from_bits(uint32_t bits) {
  float f = __uint_as_float((bits >> 9) | 0x3f800000u) - 1.0f;
  float u = (f * 1.0f) + TINY_F;
  u = fmaxf(TINY_F, u);
  return -xla_logf(-xla_logf(u));
}

// ---------------- prep kernels ----------------
__global__ void k_keys(uint32_t* __restrict__ keys) {
  int t = threadIdx.x;
  if (t >= 128) return;
#if PRNG_PARTITIONABLE
  uint32_t o0, o1;
  tf2x32(0u, 1234u, 0u, (uint32_t)t, o0, o1);
  keys[2 * t] = o0; keys[2 * t + 1] = o1;
#else
  uint32_t o0, o1, a, bb;
  if (t < 64) {
    tf2x32(0u, 1234u, (uint32_t)(2 * t),     (uint32_t)(128 + 2 * t), o0, o1); a  = o0;
    tf2x32(0u, 1234u, (uint32_t)(2 * t + 1), (uint32_t)(129 + 2 * t), o0, o1); bb = o0;
  } else {
    tf2x32(0u, 1234u, (uint32_t)(2 * t - 128), (uint32_t)(2 * t),     o0, o1); a  = o1;
    tf2x32(0u, 1234u, (uint32_t)(2 * t - 127), (uint32_t)(2 * t + 1), o0, o1); bb = o1;
  }
  keys[2 * t] = a; keys[2 * t + 1] = bb;
#endif
}

__global__ void k_trans(const float* __restrict__ Wih, const float* __restrict__ Whh,
                        float* __restrict__ WihT, float* __restrict__ WhhT) {
  int idx = blockIdx.x * blockDim.x + threadIdx.x;
  if (idx < 65536) {
    int r = idx >> 7, k = idx & 127;
    WihT[k * 512 + r] = Wih[idx];
    WhhT[k * 512 + r] = Whh[idx];
  }
}

// enc_term[b][s][m] = sum_n enc[b][s][n] * Wref[m][n], sequential-n fmaf.
__global__ __launch_bounds__(128) void k_encT(const float* __restrict__ enc,
                                              const float* __restrict__ Wref,
                                              float* __restrict__ encT) {
  __shared__ float el[64 * 132];
  __shared__ float ot[64 * 129];
  int tid = threadIdx.x;
  int b  = blockIdx.x >> 1;
  int sh = blockIdx.x & 1;
  const float* eb = enc + (size_t)b * 16384 + (size_t)sh * 8192;
  for (int i = tid; i < 8192; i += 128) {
    int s = i >> 7, n = i & 127;
    el[s * 132 + n] = eb[i];
  }
  __syncthreads();
  int sl = tid & 63;
  int mh = tid >> 6;
  for (int ml = 0; ml < 64; ++ml) {
    int m = mh * 64 + ml;
    const float4* wr = (const float4*)(Wref + m * 128);   // wave-broadcast reads
    float acc = 0.0f;
#pragma unroll 8
    for (int q = 0; q < 32; ++q) {
      float4 w4 = wr[q];
      float4 e4 = *(const float4*)&el[sl * 132 + 4 * q];
      acc = fmaf(e4.x, w4.x, acc); acc = fmaf(e4.y, w4.y, acc);
      acc = fmaf(e4.z, w4.z, acc); acc = fmaf(e4.w, w4.w, acc);
    }
    ot[sl * 129 + m] = acc;
  }
  __syncthreads();
  float* op = encT + (size_t)b * 16384 + (size_t)(sh * 64) * 128;
  for (int i = tid; i < 8192; i += 128)
    op[i] = ot[(i >> 7) * 129 + (i & 127)];
}

// ---------------- main decode kernel (4 batches/block, packed + gated pipe) --
__global__ __launch_bounds__(512, 4) void k_main(
    const float* __restrict__ enc, const float* __restrict__ h0,
    const float* __restrict__ c0, const float* __restrict__ dec_first,
    const float* __restrict__ W_out, const float* __restrict__ v,
    const float* __restrict__ b_ih, const float* __restrict__ b_hh,
    const float* __restrict__ WihT, const float* __restrict__ WhhT,
    const float* __restrict__ encT, const uint32_t* __restrict__ keys,
    float* __restrict__ out) {
  // xI[k][0..3] = inp[g][k], xI[k][4..7] = h[g][k]  (broadcast-read in P1/P3)
  __shared__ float xI_s[128][8];
  __shared__ float c_s[4][128];
  __shared__ float gates_s[4][512];
  __shared__ float2 vdec2_s[4][128];   // (v[m], dec[m]) pairs
  __shared__ __align__(16) float aB_s[512][4];  // h@W_hh for NEXT step
  __shared__ float bih_s[512];
  __shared__ float bhh_s[512];
  __shared__ float v_s[128];
  __shared__ uint32_t keys_s[256];
  __shared__ int cu_s[4][128];         // compact list of unmasked positions
  __shared__ int pos_s[4][128];        // inverse: pos_s[g][s] = index in cu_s
  __shared__ float val_s[512];         // per-unit gumbel+score
  __shared__ float msk_s[512];         // per-unit masked score
  __shared__ int   sc_s[512];          // per-unit position

  const int tid  = threadIdx.x;
  const int lane = tid & 63;
  const int w    = tid >> 6;         // wave 0..7
  const int bbase = blockIdx.x * 4;

  // ---- init ----
  bih_s[tid] = b_ih[tid];
  bhh_s[tid] = b_hh[tid];
  if (tid < 256) keys_s[tid] = keys[tid];
  if (tid < 128) v_s[tid] = v[tid];
  {
    int g = tid >> 7, j = tid & 127;
    xI_s[j][g]     = dec_first[j];
    xI_s[j][4 + g] = h0[(size_t)(bbase + g) * 128 + j];
    c_s[g][j] = c0[(size_t)(bbase + g) * 128 + j];
    cu_s[g][j] = j;
    pos_s[g][j] = j;
  }
  float logp_sum = 0.0f;
  float* tour = out + 2048;
  __syncthreads();

  for (int step = 0; step < 128; ++step) {
    // ---- P1: gates = ((inp@WihT + b_ih) + h@WhhT) + b_hh
    // steps < SHADOW_FROM: full (aA+aB inline).
    // steps >= SHADOW_FROM: aA only; aB from aB_s (previous step's shadow).
    if (step < SHADOW_FROM) {
      const int r = tid;
      float aA0 = 0.0f, aA1 = 0.0f, aA2 = 0.0f, aA3 = 0.0f;
      float aB0 = 0.0f, aB1 = 0.0f, aB2 = 0.0f, aB3 = 0.0f;
      const float* pih = WihT + r;
      const float* phh = WhhT + r;
#pragma unroll 8
      for (int k = 0; k < 128; ++k) {
        float4 xi = *(const float4*)&xI_s[k][0];
        float4 xh = *(const float4*)&xI_s[k][4];
        float wih = pih[k * 512], whh = phh[k * 512];
        aA0 = fmaf(xi.x, wih, aA0);
        aA1 = fmaf(xi.y, wih, aA1);
        aA2 = fmaf(xi.z, wih, aA2);
        aA3 = fmaf(xi.w, wih, aA3);
        aB0 = fmaf(xh.x, whh, aB0);
        aB1 = fmaf(xh.y, whh, aB1);
        aB2 = fmaf(xh.z, whh, aB2);
        aB3 = fmaf(xh.w, whh, aB3);
      }
      float b1 = bih_s[r], b2 = bhh_s[r];
      gates_s[0][r] = (((aA0 + b1) + aB0) + b2);
      gates_s[1][r] = (((aA1 + b1) + aB1) + b2);
      gates_s[2][r] = (((aA2 + b1) + aB2) + b2);
      gates_s[3][r] = (((aA3 + b1) + aB3) + b2);
    } else {
      const int r = tid;
      float aA0 = 0.0f, aA1 = 0.0f, aA2 = 0.0f, aA3 = 0.0f;
      const float* pih = WihT + r;
#pragma unroll 8
      for (int k = 0; k < 128; ++k) {
        float4 xi = *(const float4*)&xI_s[k][0];
        float wih = pih[k * 512];
        aA0 = fmaf(xi.x, wih, aA0);
        aA1 = fmaf(xi.y, wih, aA1);
        aA2 = fmaf(xi.z, wih, aA2);
        aA3 = fmaf(xi.w, wih, aA3);
      }
      float b1 = bih_s[r], b2 = bhh_s[r];
      float4 aB = *(const float4*)&aB_s[r][0];
      gates_s[0][r] = (((aA0 + b1) + aB.x) + b2);
      gates_s[1][r] = (((aA1 + b1) + aB.y) + b2);
      gates_s[2][r] = (((aA2 + b1) + aB.z) + b2);
      gates_s[3][r] = (((aA3 + b1) + aB.w) + b2);
    }
    __syncthreads();

    // ---- P2: LSTM cell (exact op order), one (g,j) per thread
    {
      int g = tid >> 7, j = tid & 127;
      float gi = gates_s[g][j], gf = gates_s[g][128 + j];
      float gg = gates_s[g][256 + j], go = gates_s[g][384 + j];
      float si = xla_sigmoidf(gi), sf = xla_sigmoidf(gf), so = xla_sigmoidf(go);
      float gt = xla_tanhf(gg);
      float cold = c_s[g][j];
      float cn = (sf * cold) + (si * gt);
      c_s[g][j] = cn;
      xI_s[j][4 + g] = so * xla_tanhf(cn);
    }
    __syncthreads();

    // ---- P3: dec[g][m] = sum_k h[g][k]*W_out[k][m], sequential-k fmaf
    {
      int g = tid >> 7, m = tid & 127;
      float acc = 0.0f;
      const float* wo = W_out + m;
#pragma unroll 8
      for (int k = 0; k < 128; ++k)
        acc = fmaf(xI_s[k][4 + g], wo[k * 128], acc);
      vdec2_s[g][m] = make_float2(v_s[m], acc);
    }
    __syncthreads();

    // ---- P4a (packed units) ∥ P1b (aB for next step; only when capacity)
    const int u = 128 - step;              // unmasked count (uniform)
    const int nact = (4 * u + 63) >> 6;    // waves running P4a
    if (tid < 4 * u) {
      const int q = tid;
      int bq = (q >= u) + (q >= 2 * u) + (q >= 3 * u);
      int e  = q - bq * u;
      int sc = cu_s[bq][e];
      const int bb = bbase + bq;
      // gumbel first: pure ALU, overlaps the first e4 load window
      uint32_t kk0 = keys_s[2 * step], kk1 = keys_s[2 * step + 1];
      uint32_t j0 = (uint32_t)bb * 128u + (uint32_t)sc;
      float gmb = gumbel_from_bits(random_bits32(kk0, kk1, j0));
      const float* ep = encT + ((size_t)bb * 128 + (size_t)sc) * 128;
      float acc = 0.0f;
#pragma unroll 8
      for (int m4 = 0; m4 < 32; ++m4) {
        float4 e4 = *(const float4*)&ep[4 * m4];
        float4 vd01 = *(const float4*)&vdec2_s[bq][4 * m4];      // v0,d0,v1,d1
        float4 vd23 = *(const float4*)&vdec2_s[bq][4 * m4 + 2];  // v2,d2,v3,d3
        float t0, t1, t2, t3;
        xla_tanh2(e4.x + vd01.y, e4.y + vd01.w, t0, t1);
        xla_tanh2(e4.z + vd23.y, e4.w + vd23.w, t2, t3);
        // strict sequential accumulation over ascending m (scalar chain)
        acc = acc + (vd01.x * t0);
        acc = acc + (vd01.z * t1);
        acc = acc + (vd23.x * t2);
        acc = acc + (vd23.z * t3);
      }
      val_s[q] = gmb + acc;
      msk_s[q] = acc;                  // mask term is exactly 0.0 for unmasked
      sc_s[q]  = sc;
    } else if (w >= nact && step >= SHADOW_FROM - 1 && step < 127) {
      // P1b: aB[r][g] = sum_k h[g][k]*WhhT[k][r] for NEXT step.
      // Gate: runs only when nfree = 8-nact >= 2 (step >= 32) -> <= 4
      // rows/lane (~2.6k issue), fitting inside P4a's ~4.4k shadow.
      const int nfree = 8 - nact;
      for (int r = (w - nact) * 64 + lane; r < 512; r += nfree * 64) {
        float a0 = 0.0f, a1 = 0.0f, a2 = 0.0f, a3 = 0.0f;
        const float* phh = WhhT + r;
#pragma unroll 4
        for (int k = 0; k < 128; ++k) {
          float4 xh = *(const float4*)&xI_s[k][4];
          float whh = phh[k * 512];
          a0 = fmaf(xh.x, whh, a0);
          a1 = fmaf(xh.y, whh, a1);
          a2 = fmaf(xh.z, whh, a2);
          a3 = fmaf(xh.w, whh, a3);
        }
        float4 o; o.x = a0; o.y = a1; o.z = a2; o.w = a3;
        *(float4*)&aB_s[r][0] = o;
      }
    }
    __syncthreads();

    // ---- P4b: per-batch reduce + update (waves 0..3, batch = w).
    // Order-free argmax comparator; se over unmasked only (masked terms
    // were exactly +0.0f). Update merged here: loc is wave-uniform.
    if (w < 4) {
      const int g = w;
      const int base = g * u;
      float vaA = -INFTY_F, mkA = -INFTY_F;
      float vaB = -INFTY_F, mkB = -INFTY_F;
      int iaA = 0x7fffffff, iaB = 0x7fffffff;
      if (lane < u)      { vaA = val_s[base + lane];      iaA = sc_s[base + lane];      mkA = msk_s[base + lane]; }
      if (lane + 64 < u) { vaB = val_s[base + lane + 64]; iaB = sc_s[base + lane + 64]; mkB = msk_s[base + lane + 64]; }
      float va = vaA; int ia = iaA;
      if (vaB > va || (vaB == va && iaB < ia)) { va = vaB; ia = iaB; }
      float mx = fmaxf(mkA, mkB);
      float se = 0.0f;
#pragma unroll
      for (int off = 32; off > 0; off >>= 1) {
        float vo = __shfl_xor(va, off, 64);
        int io = __shfl_xor(ia, off, 64);
        if (vo > va || (vo == va && io < ia)) { va = vo; ia = io; }
        mx = fmaxf(mx, __shfl_xor(mx, off, 64));
      }
      if (lane < u)      se = se + expf(mkA - mx);
      if (lane + 64 < u) se = se + expf(mkB - mx);
#pragma unroll
      for (int off = 32; off > 0; off >>= 1) se = se + __shfl_xor(se, off, 64);
      const int loc = ia;              // uniform across wave after reduce
      // msel: read loc's list position BEFORE swap-remove (wave-sequential)
      int p = pos_s[g][loc];
      float msel = msk_s[base + p];
      if (lane == 0) {
        tour[(size_t)(bbase + g) * 129 + step] = (float)loc;
        if (step == 0) tour[(size_t)(bbase + g) * 129 + 128] = (float)loc;
        // O(1) swap-remove loc from compact list
        int last = cu_s[g][u - 1];
        cu_s[g][p] = last;
        pos_s[g][last] = p;
      }
      // update: next-step decoder input for this batch (2 floats/lane)
      const float* er = enc + (size_t)(bbase + g) * 16384 + (size_t)loc * 128;
      xI_s[lane][g]      = er[lane];
      xI_s[lane + 64][g] = er[lane + 64];
      // loose log-softmax (logp not fed back; threshold 3.32)
      float lse = logf(se);
      logp_sum = logp_sum + ((msel - mx) - lse);
    }
    __syncthreads();
  }

  if (w < 4 && lane == 0) out[bbase + w] = logp_sum;
}

// ---------------- host ----------------
extern "C" void kernel_launch(void* const* d_in, const int* in_sizes, int n_in,
                              void* d_out, int out_size, void* d_ws, size_t ws_size,
                              hipStream_t stream) {
  (void)in_sizes; (void)n_in; (void)out_size;
  const float* enc       = (const float*)d_in[0];
  const float* h0        = (const float*)d_in[1];
  const float* c0        = (const float*)d_in[2];
  const float* dec_first = (const float*)d_in[3];
  const float* W_ref     = (const float*)d_in[4];
  const float* W_out     = (const float*)d_in[5];
  const float* v         = (const float*)d_in[6];
  const float* W_ih      = (const float*)d_in[7];
  const float* W_hh      = (const float*)d_in[8];
  const float* b_ih      = (const float*)d_in[9];
  const float* b_hh      = (const float*)d_in[10];

  const size_t encT_elems = (size_t)2048 * 16384;
  size_t need = (encT_elems + 65536 + 65536) * sizeof(float) + 256 * sizeof(uint32_t);
  if (ws_size < need) return;

  float* encT = (float*)d_ws;
  float* WihT = encT + encT_elems;
  float* WhhT = WihT + 65536;
  uint32_t* keys = (uint32_t*)(WhhT + 65536);
  float* out = (float*)d_out;

  k_keys<<<dim3(1), dim3(128), 0, stream>>>(keys);
  k_trans<<<dim3(256), dim3(256), 0, stream>>>(W_ih, W_hh, WihT, WhhT);
  k_encT<<<dim3(4096), dim3(128), 0, stream>>>(enc, W_ref, encT);
  k_main<<<dim3(512), dim3(512), 0, stream>>>(enc, h0, c0, dec_first, W_out, v,
                                              b_ih, b_hh, WihT, WhhT, encT, keys, out);
}

// Round 17
// 5494.616 us; speedup vs baseline: 1.0530x; 1.0530x over previous
//
#include <hip/hip_runtime.h>
#include <cstdint>
#include <cstddef>

#pragma clang fp contract(off)

// ===================== round-to-round toggles =====================
#define PRNG_PARTITIONABLE 1   // confirmed correct in R1 (absmax 0.0)
// sigmoid exp-form; tanh = XLA poly clamp +-9; gemms = sequential-k fmaf;
// score reduce = strict sequential per (b,s) lane; mask compaction (R7);
// cross-batch P4 packing (R13); gated aB-shadow (R15); fdiv_rn
// (R6/R8/R11 bit-exact). R1-R16 pass.
// R17: A/B isolation of R16's bundle. KEEP update-merge-into-P4b (deletes
// 1 barrier/step); REVERT shadow gate to nfree>=3 (SHADOW_FROM 64 — R16's
// nfree>=2 gate put 4 chains/lane on free waves at steps 32-63 and
// extended the P4a barrier, R14's failure mode in miniature).
// ==================================================================

#define INFTY_F 1.0e8f
#define TINY_F 1.17549435e-38f

#define SHADOW_FROM 64   // steps >= this consume aB_s (shadow ran at step-1)

// In-range correctly-rounded f32 divide: LLVM's FDIV32 lowering minus
// div_scale/div_fixup (pass-through for normal mid-range operands; here
// q in [4.9e-3, 53], |num| <= 500). On-device bit-exact R6/R8/R11.
__device__ __forceinline__ float fdiv_rn(float n, float q) {
  float y0 = __builtin_amdgcn_rcpf(q);
  float y  = fmaf(fmaf(-q, y0, 1.0f), y0, y0);
  float r0 = n * y;
  float e0 = fmaf(-q, r0, n);
  float r1 = fmaf(e0, y, r0);
  float e1 = fmaf(-q, r1, n);
  return fmaf(e1, y, r1);
}

// ---------------- threefry2x32 (jax exact) ----------------
__device__ __forceinline__ void tf2x32(uint32_t k0, uint32_t k1, uint32_t x0, uint32_t x1,
                                       uint32_t& o0, uint32_t& o1) {
  uint32_t ks2 = k0 ^ k1 ^ 0x1BD11BDAu;
  uint32_t v0 = x0 + k0, v1 = x1 + k1;
#define TF_R(r) { v0 += v1; v1 = (v1 << (r)) | (v1 >> (32 - (r))); v1 ^= v0; }
  TF_R(13) TF_R(15) TF_R(26) TF_R(6)
  v0 += k1;  v1 += ks2 + 1u;
  TF_R(17) TF_R(29) TF_R(16) TF_R(24)
  v0 += ks2; v1 += k0 + 2u;
  TF_R(13) TF_R(15) TF_R(26) TF_R(6)
  v0 += k0;  v1 += k1 + 3u;
  TF_R(17) TF_R(29) TF_R(16) TF_R(24)
  v0 += k1;  v1 += ks2 + 4u;
  TF_R(13) TF_R(15) TF_R(26) TF_R(6)
  v0 += ks2; v1 += k0 + 5u;
#undef TF_R
  o0 = v0; o1 = v1;
}

__device__ __forceinline__ uint32_t random_bits32(uint32_t k0, uint32_t k1, uint32_t j) {
#if PRNG_PARTITIONABLE
  uint32_t o0, o1;
  tf2x32(k0, k1, 0u, j, o0, o1);
  return o0 ^ o1;
#else
  uint32_t o0, o1;
  if (j < 131072u) { tf2x32(k0, k1, j, j + 131072u, o0, o1); return o0; }
  else             { tf2x32(k0, k1, j - 131072u, j, o0, o1); return o1; }
#endif
}

// ---------------- XLA math replicas ----------------
__device__ __forceinline__ float xla_tanhf(float x) {
  float xc = fminf(fmaxf(x, -9.0f), 9.0f);
  float x2 = xc * xc;
  float p = -2.76076847742355e-16f;
  p = (p * x2) + 2.00018790482477e-13f;
  p = (p * x2) + -8.60467152213735e-11f;
  p = (p * x2) + 5.12229709037114e-08f;
  p = (p * x2) + 1.48572235717979e-05f;
  p = (p * x2) + 6.37261928875436e-04f;
  p = (p * x2) + 4.89352455891786e-03f;
  float num = xc * p;
  float q = 1.19825839466702e-06f;
  q = (q * x2) + 1.18534705686654e-04f;
  q = (q * x2) + 2.26843463243900e-03f;
  q = (q * x2) + 4.89352518554385e-03f;
  float r = fdiv_rn(num, q);           // q in [4.9e-3, 53]: verified range
  return (fabsf(x) < 0.0004f) ? x : r;
}

// scalar-pair tanh used in P4; per-element ops IEEE-identical to xla_tanhf.
__device__ __forceinline__ void xla_tanh2(float xa, float xb, float& ra, float& rb) {
  float xca = fminf(fmaxf(xa, -9.0f), 9.0f);
  float xcb = fminf(fmaxf(xb, -9.0f), 9.0f);
  float x2a = xca * xca, x2b = xcb * xcb;
  float pa = -2.76076847742355e-16f, pb = -2.76076847742355e-16f;
  pa = (pa * x2a) + 2.00018790482477e-13f;  pb = (pb * x2b) + 2.00018790482477e-13f;
  pa = (pa * x2a) + -8.60467152213735e-11f; pb = (pb * x2b) + -8.60467152213735e-11f;
  pa = (pa * x2a) + 5.12229709037114e-08f;  pb = (pb * x2b) + 5.12229709037114e-08f;
  pa = (pa * x2a) + 1.48572235717979e-05f;  pb = (pb * x2b) + 1.48572235717979e-05f;
  pa = (pa * x2a) + 6.37261928875436e-04f;  pb = (pb * x2b) + 6.37261928875436e-04f;
  pa = (pa * x2a) + 4.89352455891786e-03f;  pb = (pb * x2b) + 4.89352455891786e-03f;
  float na = xca * pa, nb = xcb * pb;
  float qa = 1.19825839466702e-06f, qb = 1.19825839466702e-06f;
  qa = (qa * x2a) + 1.18534705686654e-04f; qb = (qb * x2b) + 1.18534705686654e-04f;
  qa = (qa * x2a) + 2.26843463243900e-03f; qb = (qb * x2b) + 2.26843463243900e-03f;
  qa = (qa * x2a) + 4.89352518554385e-03f; qb = (qb * x2b) + 4.89352518554385e-03f;
  float da = fdiv_rn(na, qa), db = fdiv_rn(nb, qb);
  ra = (fabsf(xa) < 0.0004f) ? xa : da;
  rb = (fabsf(xb) < 0.0004f) ? xb : db;
}

__device__ __forceinline__ float xla_expf(float x) {
  x = fminf(x, 88.3762626647950f);
  x = fmaxf(x, -88.3762626647949f);
  float m = floorf((x * 1.44269504088896341f) + 0.5f);
  float r = x - (m * 0.693359375f);
  r = r - (m * -2.12194440e-4f);
  float r2 = r * r;
  float y = 1.9875691500E-4f;
  y = (y * r) + 1.3981999507E-3f;
  y = (y * r) + 8.3334519073E-3f;
  y = (y * r) + 4.1665795894E-2f;
  y = (y * r) + 1.6666665459E-1f;
  y = (y * r) + 5.0000001201E-1f;
  y = (y * r2) + r;
  y = y + 1.0f;
  int mi = (int)m;
  float s = __uint_as_float((uint32_t)((mi + 127) << 23));
  return y * s;
}

__device__ __forceinline__ float xla_sigmoidf(float x) {
  return 1.0f / (1.0f + xla_expf(-x));   // keep compiler div (denom can be huge)
}

__device__ __forceinline__ float xla_logf(float x) {
  uint32_t b = __float_as_uint(x);
  float e = (float)((int)(b >> 23) - 126);
  float m = __uint_as_float((b & 0x007fffffu) | 0x3f000000u);
  bool mlt = (m < 0.707106781186547524f);
  float tmp = mlt ? m : 0.0f;
  e = e - (mlt ? 1.0f : 0.0f);
  float xx = (m - 1.0f) + tmp;
  float z = xx * xx;
  float y = 7.0376836292E-2f;
  y = (y * xx) + -1.1514610310E-1f;
  y = (y * xx) + 1.1676998740E-1f;
  y = (y * xx) + -1.2420140846E-1f;
  y = (y * xx) + 1.4249322787E-1f;
  y = (y * xx) + -1.6668057665E-1f;
  y = (y * xx) + 2.0000714765E-1f;
  y = (y * xx) + -2.4999993993E-1f;
  y = (y * xx) + 3.3333331174E-1f;
  y = y * xx;
  y = y * z;
  y = y + (e * -2.12194440e-4f);
  y = y - (z * 0.5f);
  float res = xx + y;
  res = res + (e * 0.693359375f);
  return res;
}

__device__ __forceinline__ float gumbel_from_bits(uint32_t bits) {
  float f = __uint_as_float((bits >> 9) | 0x3f800000u) - 1.0f;
  float u = (f * 1.0f) + TINY_F;
  u = fmaxf(TINY_F, u);
  return -xla_logf(-xla_logf(u));
}

// ---------------- prep kernels ----------------
__global__ void k_keys(uint32_t* __restrict__ keys) {
  int t = threadIdx.x;
  if (t >= 128) return;
#if PRNG_PARTITIONABLE
  uint32_t o0, o1;
  tf2x32(0u, 1234u, 0u, (uint32_t)t, o0, o1);
  keys[2 * t] = o0; keys[2 * t + 1] = o1;
#else
  uint32_t o0, o1, a, bb;
  if (t < 64) {
    tf2x32(0u, 1234u, (uint32_t)(2 * t),     (uint32_t)(128 + 2 * t), o0, o1); a  = o0;
    tf2x32(0u, 1234u, (uint32_t)(2 * t + 1), (uint32_t)(129 + 2 * t), o0, o1); bb = o0;
  } else {
    tf2x32(0u, 1234u, (uint32_t)(2 * t - 128), (uint32_t)(2 * t),     o0, o1); a  = o1;
    tf2x32(0u, 1234u, (uint32_t)(2 * t - 127), (uint32_t)(2 * t + 1), o0, o1); bb = o1;
  }
  keys[2 * t] = a; keys[2 * t + 1] = bb;
#endif
}

__global__ void k_trans(const float* __restrict__ Wih, const float* __restrict__ Whh,
                        float* __restrict__ WihT, float* __restrict__ WhhT) {
  int idx = blockIdx.x * blockDim.x + threadIdx.x;
  if (idx < 65536) {
    int r = idx >> 7, k = idx & 127;
    WihT[k * 512 + r] = Wih[idx];
    WhhT[k * 512 + r] = Whh[idx];
  }
}

// enc_term[b][s][m] = sum_n enc[b][s][n] * Wref[m][n], sequential-n fmaf.
__global__ __launch_bounds__(128) void k_encT(const float* __restrict__ enc,
                                              const float* __restrict__ Wref,
                                              float* __restrict__ encT) {
  __shared__ float el[64 * 132];
  __shared__ float ot[64 * 129];
  int tid = threadIdx.x;
  int b  = blockIdx.x >> 1;
  int sh = blockIdx.x & 1;
  const float* eb = enc + (size_t)b * 16384 + (size_t)sh * 8192;
  for (int i = tid; i < 8192; i += 128) {
    int s = i >> 7, n = i & 127;
    el[s * 132 + n] = eb[i];
  }
  __syncthreads();
  int sl = tid & 63;
  int mh = tid >> 6;
  for (int ml = 0; ml < 64; ++ml) {
    int m = mh * 64 + ml;
    const float4* wr = (const float4*)(Wref + m * 128);   // wave-broadcast reads
    float acc = 0.0f;
#pragma unroll 8
    for (int q = 0; q < 32; ++q) {
      float4 w4 = wr[q];
      float4 e4 = *(const float4*)&el[sl * 132 + 4 * q];
      acc = fmaf(e4.x, w4.x, acc); acc = fmaf(e4.y, w4.y, acc);
      acc = fmaf(e4.z, w4.z, acc); acc = fmaf(e4.w, w4.w, acc);
    }
    ot[sl * 129 + m] = acc;
  }
  __syncthreads();
  float* op = encT + (size_t)b * 16384 + (size_t)(sh * 64) * 128;
  for (int i = tid; i < 8192; i += 128)
    op[i] = ot[(i >> 7) * 129 + (i & 127)];
}

// ---------------- main decode kernel (4 batches/block, packed + gated pipe) --
__global__ __launch_bounds__(512, 4) void k_main(
    const float* __restrict__ enc, const float* __restrict__ h0,
    const float* __restrict__ c0, const float* __restrict__ dec_first,
    const float* __restrict__ W_out, const float* __restrict__ v,
    const float* __restrict__ b_ih, const float* __restrict__ b_hh,
    const float* __restrict__ WihT, const float* __restrict__ WhhT,
    const float* __restrict__ encT, const uint32_t* __restrict__ keys,
    float* __restrict__ out) {
  // xI[k][0..3] = inp[g][k], xI[k][4..7] = h[g][k]  (broadcast-read in P1/P3)
  __shared__ float xI_s[128][8];
  __shared__ float c_s[4][128];
  __shared__ float gates_s[4][512];
  __shared__ float2 vdec2_s[4][128];   // (v[m], dec[m]) pairs
  __shared__ __align__(16) float aB_s[512][4];  // h@W_hh for NEXT step
  __shared__ float bih_s[512];
  __shared__ float bhh_s[512];
  __shared__ float v_s[128];
  __shared__ uint32_t keys_s[256];
  __shared__ int cu_s[4][128];         // compact list of unmasked positions
  __shared__ int pos_s[4][128];        // inverse: pos_s[g][s] = index in cu_s
  __shared__ float val_s[512];         // per-unit gumbel+score
  __shared__ float msk_s[512];         // per-unit masked score
  __shared__ int   sc_s[512];          // per-unit position

  const int tid  = threadIdx.x;
  const int lane = tid & 63;
  const int w    = tid >> 6;         // wave 0..7
  const int bbase = blockIdx.x * 4;

  // ---- init ----
  bih_s[tid] = b_ih[tid];
  bhh_s[tid] = b_hh[tid];
  if (tid < 256) keys_s[tid] = keys[tid];
  if (tid < 128) v_s[tid] = v[tid];
  {
    int g = tid >> 7, j = tid & 127;
    xI_s[j][g]     = dec_first[j];
    xI_s[j][4 + g] = h0[(size_t)(bbase + g) * 128 + j];
    c_s[g][j] = c0[(size_t)(bbase + g) * 128 + j];
    cu_s[g][j] = j;
    pos_s[g][j] = j;
  }
  float logp_sum = 0.0f;
  float* tour = out + 2048;
  __syncthreads();

  for (int step = 0; step < 128; ++step) {
    // ---- P1: gates = ((inp@WihT + b_ih) + h@WhhT) + b_hh
    // steps < SHADOW_FROM: full (aA+aB inline).
    // steps >= SHADOW_FROM: aA only; aB from aB_s (previous step's shadow).
    if (step < SHADOW_FROM) {
      const int r = tid;
      float aA0 = 0.0f, aA1 = 0.0f, aA2 = 0.0f, aA3 = 0.0f;
      float aB0 = 0.0f, aB1 = 0.0f, aB2 = 0.0f, aB3 = 0.0f;
      const float* pih = WihT + r;
      const float* phh = WhhT + r;
#pragma unroll 8
      for (int k = 0; k < 128; ++k) {
        float4 xi = *(const float4*)&xI_s[k][0];
        float4 xh = *(const float4*)&xI_s[k][4];
        float wih = pih[k * 512], whh = phh[k * 512];
        aA0 = fmaf(xi.x, wih, aA0);
        aA1 = fmaf(xi.y, wih, aA1);
        aA2 = fmaf(xi.z, wih, aA2);
        aA3 = fmaf(xi.w, wih, aA3);
        aB0 = fmaf(xh.x, whh, aB0);
        aB1 = fmaf(xh.y, whh, aB1);
        aB2 = fmaf(xh.z, whh, aB2);
        aB3 = fmaf(xh.w, whh, aB3);
      }
      float b1 = bih_s[r], b2 = bhh_s[r];
      gates_s[0][r] = (((aA0 + b1) + aB0) + b2);
      gates_s[1][r] = (((aA1 + b1) + aB1) + b2);
      gates_s[2][r] = (((aA2 + b1) + aB2) + b2);
      gates_s[3][r] = (((aA3 + b1) + aB3) + b2);
    } else {
      const int r = tid;
      float aA0 = 0.0f, aA1 = 0.0f, aA2 = 0.0f, aA3 = 0.0f;
      const float* pih = WihT + r;
#pragma unroll 8
      for (int k = 0; k < 128; ++k) {
        float4 xi = *(const float4*)&xI_s[k][0];
        float wih = pih[k * 512];
        aA0 = fmaf(xi.x, wih, aA0);
        aA1 = fmaf(xi.y, wih, aA1);
        aA2 = fmaf(xi.z, wih, aA2);
        aA3 = fmaf(xi.w, wih, aA3);
      }
      float b1 = bih_s[r], b2 = bhh_s[r];
      float4 aB = *(const float4*)&aB_s[r][0];
      gates_s[0][r] = (((aA0 + b1) + aB.x) + b2);
      gates_s[1][r] = (((aA1 + b1) + aB.y) + b2);
      gates_s[2][r] = (((aA2 + b1) + aB.z) + b2);
      gates_s[3][r] = (((aA3 + b1) + aB.w) + b2);
    }
    __syncthreads();

    // ---- P2: LSTM cell (exact op order), one (g,j) per thread
    {
      int g = tid >> 7, j = tid & 127;
      float gi = gates_s[g][j], gf = gates_s[g][128 + j];
      float gg = gates_s[g][256 + j], go = gates_s[g][384 + j];
      float si = xla_sigmoidf(gi), sf = xla_sigmoidf(gf), so = xla_sigmoidf(go);
      float gt = xla_tanhf(gg);
      float cold = c_s[g][j];
      float cn = (sf * cold) + (si * gt);
      c_s[g][j] = cn;
      xI_s[j][4 + g] = so * xla_tanhf(cn);
    }
    __syncthreads();

    // ---- P3: dec[g][m] = sum_k h[g][k]*W_out[k][m], sequential-k fmaf
    {
      int g = tid >> 7, m = tid & 127;
      float acc = 0.0f;
      const float* wo = W_out + m;
#pragma unroll 8
      for (int k = 0; k < 128; ++k)
        acc = fmaf(xI_s[k][4 + g], wo[k * 128], acc);
      vdec2_s[g][m] = make_float2(v_s[m], acc);
    }
    __syncthreads();

    // ---- P4a (packed units) ∥ P1b (aB for next step; only when capacity)
    const int u = 128 - step;              // unmasked count (uniform)
    const int nact = (4 * u + 63) >> 6;    // waves running P4a
    if (tid < 4 * u) {
      const int q = tid;
      int bq = (q >= u) + (q >= 2 * u) + (q >= 3 * u);
      int e  = q - bq * u;
      int sc = cu_s[bq][e];
      const int bb = bbase + bq;
      // gumbel first: pure ALU, overlaps the first e4 load window
      uint32_t kk0 = keys_s[2 * step], kk1 = keys_s[2 * step + 1];
      uint32_t j0 = (uint32_t)bb * 128u + (uint32_t)sc;
      float gmb = gumbel_from_bits(random_bits32(kk0, kk1, j0));
      const float* ep = encT + ((size_t)bb * 128 + (size_t)sc) * 128;
      float acc = 0.0f;
#pragma unroll 8
      for (int m4 = 0; m4 < 32; ++m4) {
        float4 e4 = *(const float4*)&ep[4 * m4];
        float4 vd01 = *(const float4*)&vdec2_s[bq][4 * m4];      // v0,d0,v1,d1
        float4 vd23 = *(const float4*)&vdec2_s[bq][4 * m4 + 2];  // v2,d2,v3,d3
        float t0, t1, t2, t3;
        xla_tanh2(e4.x + vd01.y, e4.y + vd01.w, t0, t1);
        xla_tanh2(e4.z + vd23.y, e4.w + vd23.w, t2, t3);
        // strict sequential accumulation over ascending m (scalar chain)
        acc = acc + (vd01.x * t0);
        acc = acc + (vd01.z * t1);
        acc = acc + (vd23.x * t2);
        acc = acc + (vd23.z * t3);
      }
      val_s[q] = gmb + acc;
      msk_s[q] = acc;                  // mask term is exactly 0.0 for unmasked
      sc_s[q]  = sc;
    } else if (w >= nact && step >= SHADOW_FROM - 1 && step < 127) {
      // P1b: aB[r][g] = sum_k h[g][k]*WhhT[k][r] for NEXT step.
      // Gate: nfree = 8-nact >= 3 (u <= 65) -> <= 3 rows/lane, fitting
      // inside P4a's m-loop shadow (R14/R16 lesson: balance!).
      const int nfree = 8 - nact;
      for (int r = (w - nact) * 64 + lane; r < 512; r += nfree * 64) {
        float a0 = 0.0f, a1 = 0.0f, a2 = 0.0f, a3 = 0.0f;
        const float* phh = WhhT + r;
#pragma unroll 4
        for (int k = 0; k < 128; ++k) {
          float4 xh = *(const float4*)&xI_s[k][4];
          float whh = phh[k * 512];
          a0 = fmaf(xh.x, whh, a0);
          a1 = fmaf(xh.y, whh, a1);
          a2 = fmaf(xh.z, whh, a2);
          a3 = fmaf(xh.w, whh, a3);
        }
        float4 o; o.x = a0; o.y = a1; o.z = a2; o.w = a3;
        *(float4*)&aB_s[r][0] = o;
      }
    }
    __syncthreads();

    // ---- P4b: per-batch reduce + update (waves 0..3, batch = w).
    // Order-free argmax comparator; se over unmasked only (masked terms
    // were exactly +0.0f). Update merged here: loc is wave-uniform.
    if (w < 4) {
      const int g = w;
      const int base = g * u;
      float vaA = -INFTY_F, mkA = -INFTY_F;
      float vaB = -INFTY_F, mkB = -INFTY_F;
      int iaA = 0x7fffffff, iaB = 0x7fffffff;
      if (lane < u)      { vaA = val_s[base + lane];      iaA = sc_s[base + lane];      mkA = msk_s[base + lane]; }
      if (lane + 64 < u) { vaB = val_s[base + lane + 64]; iaB = sc_s[base + lane + 64]; mkB = msk_s[base + lane + 64]; }
      float va = vaA; int ia = iaA;
      if (vaB > va || (vaB == va && iaB < ia)) { va = vaB; ia = iaB; }
      float mx = fmaxf(mkA, mkB);
      float se = 0.0f;
#pragma unroll
      for (int off = 32; off > 0; off >>= 1) {
        float vo = __shfl_xor(va, off, 64);
        int io = __shfl_xor(ia, off, 64);
        if (vo > va || (vo == va && io < ia)) { va = vo; ia = io; }
        mx = fmaxf(mx, __shfl_xor(mx, off, 64));
      }
      if (lane < u)      se = se + expf(mkA - mx);
      if (lane + 64 < u) se = se + expf(mkB - mx);
#pragma unroll
      for (int off = 32; off > 0; off >>= 1) se = se + __shfl_xor(se, off, 64);
      const int loc = ia;              // uniform across wave after reduce
      // msel: read loc's list position BEFORE swap-remove (wave-sequential)
      int p = pos_s[g][loc];
      float msel = msk_s[base + p];
      if (lane == 0) {
        tour[(size_t)(bbase + g) * 129 + step] = (float)loc;
        if (step == 0) tour[(size_t)(bbase + g) * 129 + 128] = (float)loc;
        // O(1) swap-remove loc from compact list
        int last = cu_s[g][u - 1];
        cu_s[g][p] = last;
        pos_s[g][last] = p;
      }
      // update: next-step decoder input for this batch (2 floats/lane)
      const float* er = enc + (size_t)(bbase + g) * 16384 + (size_t)loc * 128;
      xI_s[lane][g]      = er[lane];
      xI_s[lane + 64][g] = er[lane + 64];
      // loose log-softmax (logp not fed back; threshold 3.32)
      float lse = logf(se);
      logp_sum = logp_sum + ((msel - mx) - lse);
    }
    __syncthreads();
  }

  if (w < 4 && lane == 0) out[bbase + w] = logp_sum;
}

// ---------------- host ----------------
extern "C" void kernel_launch(void* const* d_in, const int* in_sizes, int n_in,
                              void* d_out, int out_size, void* d_ws, size_t ws_size,
                              hipStream_t stream) {
  (void)in_sizes; (void)n_in; (void)out_size;
  const float* enc       = (const float*)d_in[0];
  const float* h0        = (const float*)d_in[1];
  const float* c0        = (const float*)d_in[2];
  const float* dec_first = (const float*)d_in[3];
  const float* W_ref     = (const float*)d_in[4];
  const float* W_out     = (const float*)d_in[5];
  const float* v         = (const float*)d_in[6];
  const float* W_ih      = (const float*)d_in[7];
  const float* W_hh      = (const float*)d_in[8];
  const float* b_ih      = (const float*)d_in[9];
  const float* b_hh      = (const float*)d_in[10];

  const size_t encT_elems = (size_t)2048 * 16384;
  size_t need = (encT_elems + 65536 + 65536) * sizeof(float) + 256 * sizeof(uint32_t);
  if (ws_size < need) return;

  float* encT = (float*)d_ws;
  float* WihT = encT + encT_elems;
  float* WhhT = WihT + 65536;
  uint32_t* keys = (uint32_t*)(WhhT + 65536);
  float* out = (float*)d_out;

  k_keys<<<dim3(1), dim3(128), 0, stream>>>(keys);
  k_trans<<<dim3(256), dim3(256), 0, stream>>>(W_ih, W_hh, WihT, WhhT);
  k_encT<<<dim3(4096), dim3(128), 0, stream>>>(enc, W_ref, encT);
  k_main<<<dim3(512), dim3(512), 0, stream>>>(enc, h0, c0, dec_first, W_out, v,
                                              b_ih, b_hh, WihT, WhhT, encT, keys, out);
}